// Round 1
// baseline (4797.613 us; speedup 1.0000x reference)
//
#include <hip/hip_runtime.h>

// Problem constants (match reference)
#define NV 100000
#define NE 400000
#define BB 4
#define NSUB 10
constexpr float DT        = 0.01f;
constexpr float K_SPRING  = 1000.0f;
constexpr float DAMP      = 0.999f;
constexpr float ACT_SCALE = 0.1f;
constexpr float EPS       = 1e-6f;

// d_out layout: pos[B][NSUB+1][NV][3] followed by vel[B][NSUB+1][NV][3]
__device__ __forceinline__ int traj_idx(int b, int s, int v, int c) {
    return ((b * (NSUB + 1) + s) * NV + v) * 3 + c;
}

__global__ void init_kernel(const float* __restrict__ pos0,
                            const float* __restrict__ vel0,
                            float* __restrict__ out,
                            float* __restrict__ force) {
    int gid = blockIdx.x * blockDim.x + threadIdx.x;
    const int total = BB * NV * 3;
    if (gid >= total) return;
    int c = gid % 3;
    int v = (gid / 3) % NV;
    int b = gid / (3 * NV);
    const int velBase = BB * (NSUB + 1) * NV * 3;
    int o = traj_idx(b, 0, v, c);
    out[o]           = pos0[gid];
    out[velBase + o] = vel0[gid];
    force[gid] = 0.0f;   // self-contained: ws is poisoned 0xAA by harness
}

__global__ void edge_kernel(const float* __restrict__ out,      // trajectory base (pos part)
                            const float* __restrict__ action,   // [B][NE]
                            const float* __restrict__ rest_len, // [NE]
                            const int2* __restrict__ edges,     // [NE]
                            float* __restrict__ force,          // [B][NV][3]
                            int s) {
    int gid = blockIdx.x * blockDim.x + threadIdx.x;
    if (gid >= BB * NE) return;
    int e = gid % NE;
    int b = gid / NE;

    int2 ed = edges[e];
    int i = ed.x, j = ed.y;

    const float* pos = out + (size_t)(b * (NSUB + 1) + s) * NV * 3;
    float pix = pos[i * 3 + 0], piy = pos[i * 3 + 1], piz = pos[i * 3 + 2];
    float pjx = pos[j * 3 + 0], pjy = pos[j * 3 + 1], pjz = pos[j * 3 + 2];

    float dx = pjx - pix, dy = pjy - piy, dz = pjz - piz;
    float len = sqrtf(dx * dx + dy * dy + dz * dz + EPS);
    float rest = rest_len[e] * (1.0f + ACT_SCALE * tanhf(action[b * NE + e]));
    float coef = K_SPRING * (len - rest) / len;
    float fx = coef * dx, fy = coef * dy, fz = coef * dz;

    float* fi = force + (size_t)(b * NV + i) * 3;
    float* fj = force + (size_t)(b * NV + j) * 3;
    atomicAdd(fi + 0,  fx); atomicAdd(fi + 1,  fy); atomicAdd(fi + 2,  fz);
    atomicAdd(fj + 0, -fx); atomicAdd(fj + 1, -fy); atomicAdd(fj + 2, -fz);
}

__global__ void node_kernel(float* __restrict__ out,
                            float* __restrict__ force,
                            int s) {
    int gid = blockIdx.x * blockDim.x + threadIdx.x;
    const int total = BB * NV * 3;
    if (gid >= total) return;
    int c = gid % 3;
    int v = (gid / 3) % NV;
    int b = gid / (3 * NV);
    const int velBase = BB * (NSUB + 1) * NV * 3;

    int cur = traj_idx(b, s, v, c);
    int nxt = traj_idx(b, s + 1, v, c);

    float f = force[gid];
    force[gid] = 0.0f;                       // ready for next substep
    float g = (c == 1) ? -9.8f : 0.0f;
    float vn = (out[velBase + cur] + DT * (f + g)) * DAMP;
    float pn = out[cur] + DT * vn;
    out[velBase + nxt] = vn;
    out[nxt] = pn;
}

extern "C" void kernel_launch(void* const* d_in, const int* in_sizes, int n_in,
                              void* d_out, int out_size, void* d_ws, size_t ws_size,
                              hipStream_t stream) {
    const float* action   = (const float*)d_in[0];
    const float* pos0     = (const float*)d_in[1];
    const float* vel0     = (const float*)d_in[2];
    const float* rest_len = (const float*)d_in[3];
    const int2*  edges    = (const int2*)d_in[4];
    float* out   = (float*)d_out;
    float* force = (float*)d_ws;   // B*NV*3 floats = 4.8 MB

    const int nNode = BB * NV * 3;
    const int nEdge = BB * NE;

    init_kernel<<<(nNode + 255) / 256, 256, 0, stream>>>(pos0, vel0, out, force);
    for (int s = 0; s < NSUB; ++s) {
        edge_kernel<<<(nEdge + 255) / 256, 256, 0, stream>>>(out, action, rest_len, edges, force, s);
        node_kernel<<<(nNode + 255) / 256, 256, 0, stream>>>(out, force, s);
    }
}

// Round 2
// 1405.311 us; speedup vs baseline: 3.4139x; 3.4139x over previous
//
#include <hip/hip_runtime.h>

// Problem constants (match reference)
#define NV 100000
#define NE 400000
#define BB 4
#define NSUB 10
constexpr float DT        = 0.01f;
constexpr float K_SPRING  = 1000.0f;
constexpr float DAMP      = 0.999f;
constexpr float ACT_SCALE = 0.1f;
constexpr float EPS       = 1e-6f;

// d_out layout: pos[B][NSUB+1][NV][3] then vel[B][NSUB+1][NV][3]
#define VEL_BASE ((size_t)BB * (NSUB + 1) * NV * 3)

// ---------- one-time setup kernels ----------

__global__ void init_traj(const float* __restrict__ pos0,
                          const float* __restrict__ vel0,
                          float* __restrict__ out) {
    int gid = blockIdx.x * blockDim.x + threadIdx.x;
    const int total = BB * NV * 3;
    if (gid >= total) return;
    int b = gid / (NV * 3);
    int rem = gid - b * NV * 3;
    size_t o = (size_t)b * (NSUB + 1) * NV * 3 + rem;   // slot 0
    out[o]            = pos0[gid];
    out[VEL_BASE + o] = vel0[gid];
}

__global__ void zero_deg(int* __restrict__ deg) {
    int v = blockIdx.x * blockDim.x + threadIdx.x;
    if (v < NV) deg[v] = 0;
}

__global__ void resteff_kernel(const float* __restrict__ action,
                               const float* __restrict__ rest_len,
                               float* __restrict__ resteff) {
    int gid = blockIdx.x * blockDim.x + threadIdx.x;
    if (gid >= BB * NE) return;
    int e = gid % NE;
    resteff[gid] = rest_len[e] * (1.0f + ACT_SCALE * tanhf(action[gid]));
}

__global__ void count_kernel(const int2* __restrict__ edges, int* __restrict__ deg) {
    int e = blockIdx.x * blockDim.x + threadIdx.x;
    if (e >= NE) return;
    int2 ed = edges[e];
    atomicAdd(&deg[ed.x], 1);
    atomicAdd(&deg[ed.y], 1);
}

// single-block exclusive scan over deg[NV] -> offs[NV+1], cursor copy
__global__ void scan_kernel(const int* __restrict__ deg,
                            int* __restrict__ offs,
                            int* __restrict__ cursor) {
    __shared__ int sums[1024];
    int t = threadIdx.x;
    const int chunk = (NV + 1023) / 1024;
    int lo = t * chunk;
    int hi = lo + chunk; if (hi > NV) hi = NV; if (lo > NV) lo = NV;
    int s = 0;
    for (int v = lo; v < hi; ++v) s += deg[v];
    sums[t] = s;
    __syncthreads();
    // Hillis-Steele inclusive scan
    for (int off = 1; off < 1024; off <<= 1) {
        int val = (t >= off) ? sums[t - off] : 0;
        __syncthreads();
        if (t >= off) sums[t] += val;
        __syncthreads();
    }
    int base = (t == 0) ? 0 : sums[t - 1];
    for (int v = lo; v < hi; ++v) {
        offs[v] = base; cursor[v] = base;
        base += deg[v];
    }
    if (t == 1023) offs[NV] = base;
}

// lists[k] = {other_node, edge_index}
__global__ void fill_kernel(const int2* __restrict__ edges,
                            int* __restrict__ cursor,
                            int2* __restrict__ lists) {
    int e = blockIdx.x * blockDim.x + threadIdx.x;
    if (e >= NE) return;
    int2 ed = edges[e];
    int p = atomicAdd(&cursor[ed.x], 1);
    lists[p] = make_int2(ed.y, e);
    int q = atomicAdd(&cursor[ed.y], 1);
    lists[q] = make_int2(ed.x, e);
}

// ---------- per-substep fused gather + integrate ----------
// force on v from edge (v,other) = K*(len-rest)/len * (pos[other]-pos[v])
// identical for both endpoints -> no sign needed.
__global__ void substep_kernel(float* __restrict__ out,
                               const float* __restrict__ resteff,
                               const int2* __restrict__ lists,
                               const int* __restrict__ offs,
                               int s) {
    int gid = blockIdx.x * blockDim.x + threadIdx.x;
    if (gid >= BB * NV) return;
    int b = gid / NV;
    int v = gid - b * NV;

    const size_t posCur = ((size_t)(b * (NSUB + 1) + s)) * NV * 3;
    const size_t posNxt = posCur + (size_t)NV * 3;
    const float* pos = out + posCur;

    float px = pos[v * 3 + 0], py = pos[v * 3 + 1], pz = pos[v * 3 + 2];
    float fx = 0.f, fy = 0.f, fz = 0.f;

    int start = offs[v], end = offs[v + 1];
    const float* re = resteff + (size_t)b * NE;
    for (int k = start; k < end; ++k) {
        int2 ent = lists[k];
        int o = ent.x;
        float ox = pos[o * 3 + 0], oy = pos[o * 3 + 1], oz = pos[o * 3 + 2];
        float dx = ox - px, dy = oy - py, dz = oz - pz;
        float len = sqrtf(dx * dx + dy * dy + dz * dz + EPS);
        float coef = K_SPRING * (len - re[ent.y]) / len;
        fx += coef * dx; fy += coef * dy; fz += coef * dz;
    }

    const float* vel = out + VEL_BASE + posCur;
    float vx = (vel[v * 3 + 0] + DT * fx) * DAMP;
    float vy = (vel[v * 3 + 1] + DT * (fy - 9.8f)) * DAMP;
    float vz = (vel[v * 3 + 2] + DT * fz) * DAMP;

    out[VEL_BASE + posNxt + v * 3 + 0] = vx;
    out[VEL_BASE + posNxt + v * 3 + 1] = vy;
    out[VEL_BASE + posNxt + v * 3 + 2] = vz;
    out[posNxt + v * 3 + 0] = px + DT * vx;
    out[posNxt + v * 3 + 1] = py + DT * vy;
    out[posNxt + v * 3 + 2] = pz + DT * vz;
}

extern "C" void kernel_launch(void* const* d_in, const int* in_sizes, int n_in,
                              void* d_out, int out_size, void* d_ws, size_t ws_size,
                              hipStream_t stream) {
    const float* action   = (const float*)d_in[0];
    const float* pos0     = (const float*)d_in[1];
    const float* vel0     = (const float*)d_in[2];
    const float* rest_len = (const float*)d_in[3];
    const int2*  edges    = (const int2*)d_in[4];
    float* out = (float*)d_out;

    // workspace layout (all offsets 8B-aligned)
    char* ws = (char*)d_ws;
    float* resteff = (float*)ws;                                   // B*NE  floats = 6.4 MB
    int2*  lists   = (int2*)(ws + (size_t)BB * NE * 4);            // 2*NE int2    = 6.4 MB
    int*   deg     = (int*)(ws + (size_t)BB * NE * 4 + (size_t)2 * NE * 8);
    int*   offs    = deg + NV;                                     // NV+1 ints
    int*   cursor  = offs + NV + 1;                                // NV ints

    const int nNode3 = BB * NV * 3;
    const int nBE    = BB * NE;
    const int nBV    = BB * NV;

    init_traj<<<(nNode3 + 255) / 256, 256, 0, stream>>>(pos0, vel0, out);
    zero_deg<<<(NV + 255) / 256, 256, 0, stream>>>(deg);
    resteff_kernel<<<(nBE + 255) / 256, 256, 0, stream>>>(action, rest_len, resteff);
    count_kernel<<<(NE + 255) / 256, 256, 0, stream>>>(edges, deg);
    scan_kernel<<<1, 1024, 0, stream>>>(deg, offs, cursor);
    fill_kernel<<<(NE + 255) / 256, 256, 0, stream>>>(edges, cursor, lists);

    for (int s = 0; s < NSUB; ++s) {
        substep_kernel<<<(nBV + 255) / 256, 256, 0, stream>>>(out, resteff, lists, offs, s);
    }
}

// Round 3
// 861.537 us; speedup vs baseline: 5.5687x; 1.6312x over previous
//
#include <hip/hip_runtime.h>

// Problem constants (match reference)
#define NV 100000
#define NE 400000
#define BB 4
#define NSUB 10
constexpr float DT        = 0.01f;
constexpr float K_SPRING  = 1000.0f;
constexpr float DAMP      = 0.999f;
constexpr float ACT_SCALE = 0.1f;
constexpr float EPS       = 1e-6f;

#define VEL_BASE ((size_t)BB * (NSUB + 1) * NV * 3)
#define NBLK ((NV + 255) / 256)   // 391 blocks for per-node arrays

// ---------- one-time setup ----------

__global__ void init_traj(const float* __restrict__ pos0,
                          const float* __restrict__ vel0,
                          float* __restrict__ out) {
    int gid = blockIdx.x * blockDim.x + threadIdx.x;
    const int total = BB * NV * 3;
    if (gid >= total) return;
    int b = gid / (NV * 3);
    int rem = gid - b * NV * 3;
    size_t o = (size_t)b * (NSUB + 1) * NV * 3 + rem;   // slot 0
    out[o]            = pos0[gid];
    out[VEL_BASE + o] = vel0[gid];
}

__global__ void pos4_init(const float* __restrict__ pos0, float4* __restrict__ p4) {
    int gid = blockIdx.x * blockDim.x + threadIdx.x;
    if (gid >= BB * NV) return;
    p4[gid] = make_float4(pos0[gid * 3 + 0], pos0[gid * 3 + 1], pos0[gid * 3 + 2], 0.f);
}

__global__ void zero_deg(int* __restrict__ deg) {
    int v = blockIdx.x * blockDim.x + threadIdx.x;
    if (v < NV) deg[v] = 0;
}

__global__ void resteff_kernel(const float* __restrict__ action,
                               const float* __restrict__ rest_len,
                               float* __restrict__ resteff) {
    int gid = blockIdx.x * blockDim.x + threadIdx.x;
    if (gid >= BB * NE) return;
    int e = gid % NE;
    resteff[gid] = rest_len[e] * (1.0f + ACT_SCALE * tanhf(action[gid]));
}

__global__ void count_kernel(const int2* __restrict__ edges, int* __restrict__ deg) {
    int e = blockIdx.x * blockDim.x + threadIdx.x;
    if (e >= NE) return;
    int2 ed = edges[e];
    atomicAdd(&deg[ed.x], 1);
    atomicAdd(&deg[ed.y], 1);
}

// --- fast 3-phase exclusive scan of deg[NV] -> offs[NV+1] (+cursor copy) ---

__global__ void scan_partials(const int* __restrict__ deg, int* __restrict__ bsum) {
    __shared__ int red[256];
    int i = blockIdx.x * 256 + threadIdx.x;
    red[threadIdx.x] = (i < NV) ? deg[i] : 0;
    __syncthreads();
    for (int off = 128; off > 0; off >>= 1) {
        if (threadIdx.x < off) red[threadIdx.x] += red[threadIdx.x + off];
        __syncthreads();
    }
    if (threadIdx.x == 0) bsum[blockIdx.x] = red[0];
}

__global__ void scan_bsums(int* __restrict__ bsum) {   // NBLK <= 512
    __shared__ int s[512];
    int t = threadIdx.x;
    s[t] = (t < NBLK) ? bsum[t] : 0;
    __syncthreads();
    for (int off = 1; off < 512; off <<= 1) {
        int v = (t >= off) ? s[t - off] : 0;
        __syncthreads();
        s[t] += v;
        __syncthreads();
    }
    if (t < NBLK) bsum[t] = (t == 0) ? 0 : s[t - 1];   // exclusive
}

__global__ void scan_write(const int* __restrict__ deg, const int* __restrict__ bsum,
                           int* __restrict__ offs, int* __restrict__ cursor) {
    __shared__ int s[256];
    int i = blockIdx.x * 256 + threadIdx.x;
    int d = (i < NV) ? deg[i] : 0;
    s[threadIdx.x] = d;
    __syncthreads();
    for (int off = 1; off < 256; off <<= 1) {          // inclusive scan
        int v = (threadIdx.x >= off) ? s[threadIdx.x - off] : 0;
        __syncthreads();
        s[threadIdx.x] += v;
        __syncthreads();
    }
    if (i <= NV - 1) {
        int excl = bsum[blockIdx.x] + s[threadIdx.x] - d;
        offs[i] = excl; cursor[i] = excl;
        if (i == NV - 1) offs[NV] = excl + d;
    }
}

// ---------- adjacency fill ----------
// FAT: blists[b][k] = {as_float(other), rest_eff[b][edge]}  (per-batch)
// LEAN: lists[k] = {other, edge}
__global__ void fill_fat(const int2* __restrict__ edges,
                         const float* __restrict__ resteff,
                         int* __restrict__ cursor,
                         float2* __restrict__ blists) {
    int e = blockIdx.x * blockDim.x + threadIdx.x;
    if (e >= NE) return;
    int2 ed = edges[e];
    int p = atomicAdd(&cursor[ed.x], 1);
    int q = atomicAdd(&cursor[ed.y], 1);
    #pragma unroll
    for (int b = 0; b < BB; ++b) {
        float re = resteff[b * NE + e];
        float2* bl = blists + (size_t)b * 2 * NE;
        bl[p] = make_float2(__int_as_float(ed.y), re);
        bl[q] = make_float2(__int_as_float(ed.x), re);
    }
}

__global__ void fill_lean(const int2* __restrict__ edges,
                          int* __restrict__ cursor,
                          int2* __restrict__ lists) {
    int e = blockIdx.x * blockDim.x + threadIdx.x;
    if (e >= NE) return;
    int2 ed = edges[e];
    int p = atomicAdd(&cursor[ed.x], 1);
    lists[p] = make_int2(ed.y, e);
    int q = atomicAdd(&cursor[ed.y], 1);
    lists[q] = make_int2(ed.x, e);
}

// ---------- per-substep fused gather + integrate ----------
template <bool FAT>
__global__ void substep_kernel(float* __restrict__ out,
                               const float4* __restrict__ posc,
                               float4* __restrict__ posn,
                               const float2* __restrict__ blists,  // FAT
                               const int2* __restrict__ lists,     // LEAN
                               const float* __restrict__ resteff,  // LEAN
                               const int* __restrict__ offs, int s) {
    int gid = blockIdx.x * blockDim.x + threadIdx.x;
    if (gid >= BB * NV) return;
    int b = gid / NV;
    int v = gid - b * NV;

    const float4* pb = posc + (size_t)b * NV;
    float4 p = pb[v];
    float fx = 0.f, fy = 0.f, fz = 0.f;

    int start = offs[v], end = offs[v + 1];
    if (FAT) {
        const float2* bl = blists + (size_t)b * 2 * NE;
        for (int k = start; k < end; ++k) {
            float2 ent = bl[k];
            int o = __float_as_int(ent.x);
            float4 q = pb[o];
            float dx = q.x - p.x, dy = q.y - p.y, dz = q.z - p.z;
            float len = sqrtf(dx * dx + dy * dy + dz * dz + EPS);
            float coef = K_SPRING * (len - ent.y) / len;
            fx += coef * dx; fy += coef * dy; fz += coef * dz;
        }
    } else {
        const float* re = resteff + (size_t)b * NE;
        for (int k = start; k < end; ++k) {
            int2 ent = lists[k];
            float4 q = pb[ent.x];
            float dx = q.x - p.x, dy = q.y - p.y, dz = q.z - p.z;
            float len = sqrtf(dx * dx + dy * dy + dz * dz + EPS);
            float coef = K_SPRING * (len - re[ent.y]) / len;
            fx += coef * dx; fy += coef * dy; fz += coef * dz;
        }
    }

    const size_t posCur = ((size_t)(b * (NSUB + 1) + s)) * NV * 3;
    const size_t posNxt = posCur + (size_t)NV * 3;
    const float* vel = out + VEL_BASE + posCur;
    float vx = (vel[v * 3 + 0] + DT * fx) * DAMP;
    float vy = (vel[v * 3 + 1] + DT * (fy - 9.8f)) * DAMP;
    float vz = (vel[v * 3 + 2] + DT * fz) * DAMP;
    float pxn = p.x + DT * vx, pyn = p.y + DT * vy, pzn = p.z + DT * vz;

    out[VEL_BASE + posNxt + v * 3 + 0] = vx;
    out[VEL_BASE + posNxt + v * 3 + 1] = vy;
    out[VEL_BASE + posNxt + v * 3 + 2] = vz;
    out[posNxt + v * 3 + 0] = pxn;
    out[posNxt + v * 3 + 1] = pyn;
    out[posNxt + v * 3 + 2] = pzn;
    posn[gid] = make_float4(pxn, pyn, pzn, 0.f);
}

extern "C" void kernel_launch(void* const* d_in, const int* in_sizes, int n_in,
                              void* d_out, int out_size, void* d_ws, size_t ws_size,
                              hipStream_t stream) {
    const float* action   = (const float*)d_in[0];
    const float* pos0     = (const float*)d_in[1];
    const float* vel0     = (const float*)d_in[2];
    const float* rest_len = (const float*)d_in[3];
    const int2*  edges    = (const int2*)d_in[4];
    float* out = (float*)d_out;

    // workspace layout
    char* ws = (char*)d_ws;
    size_t off = 0;
    float* resteff = (float*)(ws + off); off += (size_t)BB * NE * 4;       // 6.4 MB
    int* deg    = (int*)(ws + off); off += (size_t)NV * 4;
    int* offs   = (int*)(ws + off); off += (size_t)(NV + 1) * 4;
    int* cursor = (int*)(ws + off); off += (size_t)NV * 4;
    int* bsum   = (int*)(ws + off); off += (size_t)(NBLK + 4) * 4;
    off = (off + 15) & ~(size_t)15;
    float4* p4a = (float4*)(ws + off); off += (size_t)BB * NV * 16;        // 6.4 MB
    float4* p4b = (float4*)(ws + off); off += (size_t)BB * NV * 16;        // 6.4 MB
    float2* blists = (float2*)(ws + off);                                  // FAT: 25.6 MB
    int2*   lists  = (int2*)(ws + off);                                    // LEAN: 6.4 MB
    const bool fat = ws_size >= off + (size_t)BB * 2 * NE * 8;

    const int nNode3 = BB * NV * 3;
    const int nBE    = BB * NE;
    const int nBV    = BB * NV;

    init_traj<<<(nNode3 + 255) / 256, 256, 0, stream>>>(pos0, vel0, out);
    pos4_init<<<(nBV + 255) / 256, 256, 0, stream>>>(pos0, p4a);
    zero_deg<<<NBLK, 256, 0, stream>>>(deg);
    resteff_kernel<<<(nBE + 255) / 256, 256, 0, stream>>>(action, rest_len, resteff);
    count_kernel<<<(NE + 255) / 256, 256, 0, stream>>>(edges, deg);
    scan_partials<<<NBLK, 256, 0, stream>>>(deg, bsum);
    scan_bsums<<<1, 512, 0, stream>>>(bsum);
    scan_write<<<NBLK, 256, 0, stream>>>(deg, bsum, offs, cursor);
    if (fat) {
        fill_fat<<<(NE + 255) / 256, 256, 0, stream>>>(edges, resteff, cursor, blists);
    } else {
        fill_lean<<<(NE + 255) / 256, 256, 0, stream>>>(edges, cursor, lists);
    }

    for (int s = 0; s < NSUB; ++s) {
        float4* pc = (s & 1) ? p4b : p4a;
        float4* pn = (s & 1) ? p4a : p4b;
        if (fat) {
            substep_kernel<true><<<(nBV + 255) / 256, 256, 0, stream>>>(
                out, pc, pn, blists, nullptr, nullptr, offs, s);
        } else {
            substep_kernel<false><<<(nBV + 255) / 256, 256, 0, stream>>>(
                out, pc, pn, nullptr, lists, resteff, offs, s);
        }
    }
}

// Round 5
// 519.757 us; speedup vs baseline: 9.2305x; 1.6576x over previous
//
#include <hip/hip_runtime.h>

// Problem constants (match reference)
#define NV 100000
#define NE 400000
#define BB 4
#define NSUB 10
constexpr float DT        = 0.01f;
constexpr float K_SPRING  = 1000.0f;
constexpr float DAMP      = 0.999f;
constexpr float ACT_SCALE = 0.1f;
constexpr float EPS       = 1e-6f;

#define VEL_BASE ((size_t)BB * (NSUB + 1) * NV * 3)
#define NBLK ((NV + 255) / 256)   // 391 blocks for per-node arrays

typedef float fv4 __attribute__((ext_vector_type(4)));
typedef int   iv2 __attribute__((ext_vector_type(2)));

// ---------- one-time setup ----------

__global__ void init_traj(const float* __restrict__ pos0,
                          const float* __restrict__ vel0,
                          float* __restrict__ out) {
    int gid = blockIdx.x * blockDim.x + threadIdx.x;
    const int total = BB * NV * 3;
    if (gid >= total) return;
    int b = gid / (NV * 3);
    int rem = gid - b * NV * 3;
    size_t o = (size_t)b * (NSUB + 1) * NV * 3 + rem;   // slot 0
    out[o]            = pos0[gid];
    out[VEL_BASE + o] = vel0[gid];
}

// posT[v*4 + b] = pos[b][v]  -> all 4 batches of one node share a 64B line
__global__ void posT_init(const float* __restrict__ pos0, float4* __restrict__ posT) {
    int gid = blockIdx.x * blockDim.x + threadIdx.x;
    if (gid >= NV * BB) return;
    int b = gid & 3, v = gid >> 2;
    const float* src = pos0 + ((size_t)b * NV + v) * 3;
    posT[gid] = make_float4(src[0], src[1], src[2], 0.f);
}

__global__ void zero_deg(int* __restrict__ deg) {
    int v = blockIdx.x * blockDim.x + threadIdx.x;
    if (v < NV) deg[v] = 0;
}

// resteffT[e] = {rest_eff[b=0..3][e]}
__global__ void resteffT_kernel(const float* __restrict__ action,
                                const float* __restrict__ rest_len,
                                fv4* __restrict__ rT) {
    int e = blockIdx.x * blockDim.x + threadIdx.x;
    if (e >= NE) return;
    float rl = rest_len[e];
    fv4 r;
    #pragma unroll
    for (int b = 0; b < BB; ++b)
        r[b] = rl * (1.0f + ACT_SCALE * tanhf(action[b * NE + e]));
    rT[e] = r;
}

__global__ void count_kernel(const int2* __restrict__ edges, int* __restrict__ deg) {
    int e = blockIdx.x * blockDim.x + threadIdx.x;
    if (e >= NE) return;
    int2 ed = edges[e];
    atomicAdd(&deg[ed.x], 1);
    atomicAdd(&deg[ed.y], 1);
}

// --- 3-phase exclusive scan of deg[NV] -> offs[NV+1] (+cursor copy) ---

__global__ void scan_partials(const int* __restrict__ deg, int* __restrict__ bsum) {
    __shared__ int red[256];
    int i = blockIdx.x * 256 + threadIdx.x;
    red[threadIdx.x] = (i < NV) ? deg[i] : 0;
    __syncthreads();
    for (int off = 128; off > 0; off >>= 1) {
        if (threadIdx.x < off) red[threadIdx.x] += red[threadIdx.x + off];
        __syncthreads();
    }
    if (threadIdx.x == 0) bsum[blockIdx.x] = red[0];
}

__global__ void scan_bsums(int* __restrict__ bsum) {   // NBLK <= 512
    __shared__ int s[512];
    int t = threadIdx.x;
    s[t] = (t < NBLK) ? bsum[t] : 0;
    __syncthreads();
    for (int off = 1; off < 512; off <<= 1) {
        int v = (t >= off) ? s[t - off] : 0;
        __syncthreads();
        s[t] += v;
        __syncthreads();
    }
    if (t < NBLK) bsum[t] = (t == 0) ? 0 : s[t - 1];   // exclusive
}

__global__ void scan_write(const int* __restrict__ deg, const int* __restrict__ bsum,
                           int* __restrict__ offs, int* __restrict__ cursor) {
    __shared__ int s[256];
    int i = blockIdx.x * 256 + threadIdx.x;
    int d = (i < NV) ? deg[i] : 0;
    s[threadIdx.x] = d;
    __syncthreads();
    for (int off = 1; off < 256; off <<= 1) {          // inclusive scan
        int v = (threadIdx.x >= off) ? s[threadIdx.x - off] : 0;
        __syncthreads();
        s[threadIdx.x] += v;
        __syncthreads();
    }
    if (i <= NV - 1) {
        int excl = bsum[blockIdx.x] + s[threadIdx.x] - d;
        offs[i] = excl; cursor[i] = excl;
        if (i == NV - 1) offs[NV] = excl + d;
    }
}

// ---------- adjacency fill ----------
// FAT:  lo[k] = other node, lre[k] = rest_eff (all 4 batches)
// LEAN: lists[k] = {other, edge}
__global__ void fill_fat(const int2* __restrict__ edges,
                         const fv4* __restrict__ rT,
                         int* __restrict__ cursor,
                         int* __restrict__ lo,
                         fv4* __restrict__ lre) {
    int e = blockIdx.x * blockDim.x + threadIdx.x;
    if (e >= NE) return;
    int2 ed = edges[e];
    fv4 re = rT[e];
    int p = atomicAdd(&cursor[ed.x], 1);
    lo[p] = ed.y; lre[p] = re;
    int q = atomicAdd(&cursor[ed.y], 1);
    lo[q] = ed.x; lre[q] = re;
}

__global__ void fill_lean(const int2* __restrict__ edges,
                          int* __restrict__ cursor,
                          int2* __restrict__ lists) {
    int e = blockIdx.x * blockDim.x + threadIdx.x;
    if (e >= NE) return;
    int2 ed = edges[e];
    int p = atomicAdd(&cursor[ed.x], 1);
    lists[p] = make_int2(ed.y, e);
    int q = atomicAdd(&cursor[ed.y], 1);
    lists[q] = make_int2(ed.x, e);
}

// ---------- per-substep fused gather + integrate, all 4 batches per thread ----------
__global__ void substep_merged(float* __restrict__ out,
                               const float4* __restrict__ posT,
                               float4* __restrict__ posTn,
                               const int* __restrict__ lo,
                               const fv4* __restrict__ lre,
                               const int* __restrict__ offs, int s) {
    int v = blockIdx.x * blockDim.x + threadIdx.x;
    if (v >= NV) return;

    float4 p[BB];
    #pragma unroll
    for (int b = 0; b < BB; ++b) p[b] = posT[v * 4 + b];
    float fx[BB] = {0,0,0,0}, fy[BB] = {0,0,0,0}, fz[BB] = {0,0,0,0};

    int start = offs[v], end = offs[v + 1];
    for (int k = start; k < end; ++k) {
        int o  = __builtin_nontemporal_load(lo + k);
        fv4 re = __builtin_nontemporal_load(lre + k);
        #pragma unroll
        for (int b = 0; b < BB; ++b) {
            float4 q = posT[o * 4 + b];
            float dx = q.x - p[b].x, dy = q.y - p[b].y, dz = q.z - p[b].z;
            float len = sqrtf(dx * dx + dy * dy + dz * dz + EPS);
            float coef = K_SPRING * (len - re[b]) / len;
            fx[b] += coef * dx; fy[b] += coef * dy; fz[b] += coef * dz;
        }
    }

    #pragma unroll
    for (int b = 0; b < BB; ++b) {
        size_t cur = ((size_t)(b * (NSUB + 1) + s)) * NV * 3 + (size_t)v * 3;
        size_t nxt = cur + (size_t)NV * 3;
        float vx = (out[VEL_BASE + cur + 0] + DT * fx[b]) * DAMP;
        float vy = (out[VEL_BASE + cur + 1] + DT * (fy[b] - 9.8f)) * DAMP;
        float vz = (out[VEL_BASE + cur + 2] + DT * fz[b]) * DAMP;
        float pxn = p[b].x + DT * vx, pyn = p[b].y + DT * vy, pzn = p[b].z + DT * vz;
        out[VEL_BASE + nxt + 0] = vx;
        out[VEL_BASE + nxt + 1] = vy;
        out[VEL_BASE + nxt + 2] = vz;
        out[nxt + 0] = pxn; out[nxt + 1] = pyn; out[nxt + 2] = pzn;
        posTn[v * 4 + b] = make_float4(pxn, pyn, pzn, 0.f);
    }
}

// LEAN fallback: per-(batch,node) thread, same posT layout
__global__ void substep_lean(float* __restrict__ out,
                             const float4* __restrict__ posT,
                             float4* __restrict__ posTn,
                             const int* __restrict__ lists,   // int pairs, element-addressed
                             const fv4* __restrict__ rT,
                             const int* __restrict__ offs, int s) {
    int gid = blockIdx.x * blockDim.x + threadIdx.x;
    if (gid >= BB * NV) return;
    int b = gid / NV;
    int v = gid - b * NV;

    float4 p = posT[v * 4 + b];
    float fx = 0.f, fy = 0.f, fz = 0.f;
    int start = offs[v], end = offs[v + 1];
    for (int k = start; k < end; ++k) {
        iv2 ent = __builtin_nontemporal_load((const iv2*)(lists + 2 * (size_t)k));
        float4 q = posT[ent.x * 4 + b];
        float re = ((const float*)&rT[ent.y])[b];
        float dx = q.x - p.x, dy = q.y - p.y, dz = q.z - p.z;
        float len = sqrtf(dx * dx + dy * dy + dz * dz + EPS);
        float coef = K_SPRING * (len - re) / len;
        fx += coef * dx; fy += coef * dy; fz += coef * dz;
    }

    size_t cur = ((size_t)(b * (NSUB + 1) + s)) * NV * 3 + (size_t)v * 3;
    size_t nxt = cur + (size_t)NV * 3;
    float vx = (out[VEL_BASE + cur + 0] + DT * fx) * DAMP;
    float vy = (out[VEL_BASE + cur + 1] + DT * (fy - 9.8f)) * DAMP;
    float vz = (out[VEL_BASE + cur + 2] + DT * fz) * DAMP;
    float pxn = p.x + DT * vx, pyn = p.y + DT * vy, pzn = p.z + DT * vz;
    out[VEL_BASE + nxt + 0] = vx;
    out[VEL_BASE + nxt + 1] = vy;
    out[VEL_BASE + nxt + 2] = vz;
    out[nxt + 0] = pxn; out[nxt + 1] = pyn; out[nxt + 2] = pzn;
    posTn[v * 4 + b] = make_float4(pxn, pyn, pzn, 0.f);
}

extern "C" void kernel_launch(void* const* d_in, const int* in_sizes, int n_in,
                              void* d_out, int out_size, void* d_ws, size_t ws_size,
                              hipStream_t stream) {
    const float* action   = (const float*)d_in[0];
    const float* pos0     = (const float*)d_in[1];
    const float* vel0     = (const float*)d_in[2];
    const float* rest_len = (const float*)d_in[3];
    const int2*  edges    = (const int2*)d_in[4];
    float* out = (float*)d_out;

    // workspace layout
    char* ws = (char*)d_ws;
    size_t off = 0;
    fv4* rT     = (fv4*)(ws + off); off += (size_t)NE * 16;          // 6.4 MB
    int* deg    = (int*)(ws + off); off += (size_t)NV * 4;
    int* offs   = (int*)(ws + off); off += (size_t)(NV + 1) * 4;
    int* cursor = (int*)(ws + off); off += (size_t)NV * 4;
    int* bsum   = (int*)(ws + off); off += (size_t)(NBLK + 4) * 4;
    off = (off + 63) & ~(size_t)63;
    float4* pTa = (float4*)(ws + off); off += (size_t)NV * BB * 16;  // 6.4 MB
    float4* pTb = (float4*)(ws + off); off += (size_t)NV * BB * 16;  // 6.4 MB
    int* lo  = (int*)(ws + off);
    size_t lre_off = off + (size_t)2 * NE * 4;
    fv4* lre = (fv4*)(ws + lre_off);
    const bool fat = ws_size >= lre_off + (size_t)2 * NE * 16;       // needs ~36.5 MB total
    int2* lists = (int2*)(ws + off);                                 // lean overlay

    const int nNode3 = BB * NV * 3;
    const int nBV    = BB * NV;

    init_traj<<<(nNode3 + 255) / 256, 256, 0, stream>>>(pos0, vel0, out);
    posT_init<<<(nBV + 255) / 256, 256, 0, stream>>>(pos0, pTa);
    zero_deg<<<NBLK, 256, 0, stream>>>(deg);
    resteffT_kernel<<<(NE + 255) / 256, 256, 0, stream>>>(action, rest_len, rT);
    count_kernel<<<(NE + 255) / 256, 256, 0, stream>>>(edges, deg);
    scan_partials<<<NBLK, 256, 0, stream>>>(deg, bsum);
    scan_bsums<<<1, 512, 0, stream>>>(bsum);
    scan_write<<<NBLK, 256, 0, stream>>>(deg, bsum, offs, cursor);
    if (fat) {
        fill_fat<<<(NE + 255) / 256, 256, 0, stream>>>(edges, rT, cursor, lo, lre);
    } else {
        fill_lean<<<(NE + 255) / 256, 256, 0, stream>>>(edges, cursor, lists);
    }

    for (int s = 0; s < NSUB; ++s) {
        float4* pc = (s & 1) ? pTb : pTa;
        float4* pn = (s & 1) ? pTa : pTb;
        if (fat) {
            substep_merged<<<NBLK, 256, 0, stream>>>(out, pc, pn, lo, lre, offs, s);
        } else {
            substep_lean<<<(nBV + 255) / 256, 256, 0, stream>>>(out, pc, pn, (const int*)lists, rT, offs, s);
        }
    }
}

// Round 6
// 474.058 us; speedup vs baseline: 10.1203x; 1.0964x over previous
//
#include <hip/hip_runtime.h>

// Problem constants (match reference)
#define NV 100000
#define NE 400000
#define BB 4
#define NSUB 10
constexpr float DT        = 0.01f;
constexpr float K_SPRING  = 1000.0f;
constexpr float DAMP      = 0.999f;
constexpr float ACT_SCALE = 0.1f;
constexpr float EPS       = 1e-6f;

#define VEL_BASE ((size_t)BB * (NSUB + 1) * NV * 3)
#define NBLK ((NV + 255) / 256)   // 391 blocks for per-node arrays

typedef float fv4 __attribute__((ext_vector_type(4)));
typedef int   iv2 __attribute__((ext_vector_type(2)));

// ---------- one-time setup ----------

__global__ void init_traj(const float* __restrict__ pos0,
                          const float* __restrict__ vel0,
                          float* __restrict__ out) {
    int gid = blockIdx.x * blockDim.x + threadIdx.x;
    const int total = BB * NV * 3;
    if (gid >= total) return;
    int b = gid / (NV * 3);
    int rem = gid - b * NV * 3;
    size_t o = (size_t)b * (NSUB + 1) * NV * 3 + rem;   // slot 0
    out[o]            = pos0[gid];
    out[VEL_BASE + o] = vel0[gid];
}

// posT[v*4 + b] = pos[b][v]  -> all 4 batches of one node share a 64B line
__global__ void posT_init(const float* __restrict__ pos0, float4* __restrict__ posT) {
    int gid = blockIdx.x * blockDim.x + threadIdx.x;
    if (gid >= NV * BB) return;
    int b = gid & 3, v = gid >> 2;
    const float* src = pos0 + ((size_t)b * NV + v) * 3;
    posT[gid] = make_float4(src[0], src[1], src[2], 0.f);
}

__global__ void zero_deg(int* __restrict__ deg) {
    int v = blockIdx.x * blockDim.x + threadIdx.x;
    if (v < NV) deg[v] = 0;
}

// resteffT[e] = {rest_eff[b=0..3][e]}
__global__ void resteffT_kernel(const float* __restrict__ action,
                                const float* __restrict__ rest_len,
                                fv4* __restrict__ rT) {
    int e = blockIdx.x * blockDim.x + threadIdx.x;
    if (e >= NE) return;
    float rl = rest_len[e];
    fv4 r;
    #pragma unroll
    for (int b = 0; b < BB; ++b)
        r[b] = rl * (1.0f + ACT_SCALE * tanhf(action[b * NE + e]));
    rT[e] = r;
}

__global__ void count_kernel(const int2* __restrict__ edges, int* __restrict__ deg) {
    int e = blockIdx.x * blockDim.x + threadIdx.x;
    if (e >= NE) return;
    int2 ed = edges[e];
    atomicAdd(&deg[ed.x], 1);
    atomicAdd(&deg[ed.y], 1);
}

// --- 3-phase exclusive scan of deg[NV] -> offs[NV+1] (+cursor copy) ---

__global__ void scan_partials(const int* __restrict__ deg, int* __restrict__ bsum) {
    __shared__ int red[256];
    int i = blockIdx.x * 256 + threadIdx.x;
    red[threadIdx.x] = (i < NV) ? deg[i] : 0;
    __syncthreads();
    for (int off = 128; off > 0; off >>= 1) {
        if (threadIdx.x < off) red[threadIdx.x] += red[threadIdx.x + off];
        __syncthreads();
    }
    if (threadIdx.x == 0) bsum[blockIdx.x] = red[0];
}

__global__ void scan_bsums(int* __restrict__ bsum) {   // NBLK <= 512
    __shared__ int s[512];
    int t = threadIdx.x;
    s[t] = (t < NBLK) ? bsum[t] : 0;
    __syncthreads();
    for (int off = 1; off < 512; off <<= 1) {
        int v = (t >= off) ? s[t - off] : 0;
        __syncthreads();
        s[t] += v;
        __syncthreads();
    }
    if (t < NBLK) bsum[t] = (t == 0) ? 0 : s[t - 1];   // exclusive
}

__global__ void scan_write(const int* __restrict__ deg, const int* __restrict__ bsum,
                           int* __restrict__ offs, int* __restrict__ cursor) {
    __shared__ int s[256];
    int i = blockIdx.x * 256 + threadIdx.x;
    int d = (i < NV) ? deg[i] : 0;
    s[threadIdx.x] = d;
    __syncthreads();
    for (int off = 1; off < 256; off <<= 1) {          // inclusive scan
        int v = (threadIdx.x >= off) ? s[threadIdx.x - off] : 0;
        __syncthreads();
        s[threadIdx.x] += v;
        __syncthreads();
    }
    if (i <= NV - 1) {
        int excl = bsum[blockIdx.x] + s[threadIdx.x] - d;
        offs[i] = excl; cursor[i] = excl;
        if (i == NV - 1) offs[NV] = excl + d;
    }
}

// ---------- adjacency fill ----------
// FAT:  lo[k] = other node, lre[k] = rest_eff (all 4 batches)
// LEAN: lists[k] = {other, edge}
__global__ void fill_fat(const int2* __restrict__ edges,
                         const fv4* __restrict__ rT,
                         int* __restrict__ cursor,
                         int* __restrict__ lo,
                         fv4* __restrict__ lre) {
    int e = blockIdx.x * blockDim.x + threadIdx.x;
    if (e >= NE) return;
    int2 ed = edges[e];
    fv4 re = rT[e];
    int p = atomicAdd(&cursor[ed.x], 1);
    lo[p] = ed.y; lre[p] = re;
    int q = atomicAdd(&cursor[ed.y], 1);
    lo[q] = ed.x; lre[q] = re;
}

__global__ void fill_lean(const int2* __restrict__ edges,
                          int* __restrict__ cursor,
                          int2* __restrict__ lists) {
    int e = blockIdx.x * blockDim.x + threadIdx.x;
    if (e >= NE) return;
    int2 ed = edges[e];
    int p = atomicAdd(&cursor[ed.x], 1);
    lists[p] = make_int2(ed.y, e);
    int q = atomicAdd(&cursor[ed.y], 1);
    lists[q] = make_int2(ed.x, e);
}

// ---------- per-substep fused gather + integrate ----------
// One thread per (node, batch); lanes 0-3 of a node cover b=0..3 so each
// neighbor gather is one fully-used 64B line: posT[o*4 + {0..3}].
__global__ void substep_il(float* __restrict__ out,
                           const float4* __restrict__ posT,
                           float4* __restrict__ posTn,
                           const int* __restrict__ lo,
                           const float* __restrict__ lre,   // element view: [k*4 + b]
                           const int* __restrict__ offs, int s) {
    int gid = blockIdx.x * blockDim.x + threadIdx.x;
    if (gid >= BB * NV) return;
    int v = gid >> 2, b = gid & 3;

    float4 p = posT[gid];
    float fx = 0.f, fy = 0.f, fz = 0.f;

    int start = offs[v], end = offs[v + 1];
    for (int k = start; k < end; ++k) {
        int   o  = __builtin_nontemporal_load(lo + k);
        float re = __builtin_nontemporal_load(lre + 4 * (size_t)k + b);
        float4 q = posT[o * 4 + b];
        float dx = q.x - p.x, dy = q.y - p.y, dz = q.z - p.z;
        float len = sqrtf(dx * dx + dy * dy + dz * dz + EPS);
        float coef = K_SPRING * (len - re) / len;
        fx += coef * dx; fy += coef * dy; fz += coef * dz;
    }

    size_t cur = ((size_t)(b * (NSUB + 1) + s)) * NV * 3 + (size_t)v * 3;
    size_t nxt = cur + (size_t)NV * 3;
    float vx = (out[VEL_BASE + cur + 0] + DT * fx) * DAMP;
    float vy = (out[VEL_BASE + cur + 1] + DT * (fy - 9.8f)) * DAMP;
    float vz = (out[VEL_BASE + cur + 2] + DT * fz) * DAMP;
    float pxn = p.x + DT * vx, pyn = p.y + DT * vy, pzn = p.z + DT * vz;
    out[VEL_BASE + nxt + 0] = vx;
    out[VEL_BASE + nxt + 1] = vy;
    out[VEL_BASE + nxt + 2] = vz;
    out[nxt + 0] = pxn; out[nxt + 1] = pyn; out[nxt + 2] = pzn;
    posTn[gid] = make_float4(pxn, pyn, pzn, 0.f);
}

// LEAN fallback: per-(batch,node) thread, same posT layout
__global__ void substep_lean(float* __restrict__ out,
                             const float4* __restrict__ posT,
                             float4* __restrict__ posTn,
                             const int* __restrict__ lists,   // int pairs, element-addressed
                             const fv4* __restrict__ rT,
                             const int* __restrict__ offs, int s) {
    int gid = blockIdx.x * blockDim.x + threadIdx.x;
    if (gid >= BB * NV) return;
    int b = gid / NV;
    int v = gid - b * NV;

    float4 p = posT[v * 4 + b];
    float fx = 0.f, fy = 0.f, fz = 0.f;
    int start = offs[v], end = offs[v + 1];
    for (int k = start; k < end; ++k) {
        iv2 ent = __builtin_nontemporal_load((const iv2*)(lists + 2 * (size_t)k));
        float4 q = posT[ent.x * 4 + b];
        float re = ((const float*)&rT[ent.y])[b];
        float dx = q.x - p.x, dy = q.y - p.y, dz = q.z - p.z;
        float len = sqrtf(dx * dx + dy * dy + dz * dz + EPS);
        float coef = K_SPRING * (len - re) / len;
        fx += coef * dx; fy += coef * dy; fz += coef * dz;
    }

    size_t cur = ((size_t)(b * (NSUB + 1) + s)) * NV * 3 + (size_t)v * 3;
    size_t nxt = cur + (size_t)NV * 3;
    float vx = (out[VEL_BASE + cur + 0] + DT * fx) * DAMP;
    float vy = (out[VEL_BASE + cur + 1] + DT * (fy - 9.8f)) * DAMP;
    float vz = (out[VEL_BASE + cur + 2] + DT * fz) * DAMP;
    float pxn = p.x + DT * vx, pyn = p.y + DT * vy, pzn = p.z + DT * vz;
    out[VEL_BASE + nxt + 0] = vx;
    out[VEL_BASE + nxt + 1] = vy;
    out[VEL_BASE + nxt + 2] = vz;
    out[nxt + 0] = pxn; out[nxt + 1] = pyn; out[nxt + 2] = pzn;
    posTn[v * 4 + b] = make_float4(pxn, pyn, pzn, 0.f);
}

extern "C" void kernel_launch(void* const* d_in, const int* in_sizes, int n_in,
                              void* d_out, int out_size, void* d_ws, size_t ws_size,
                              hipStream_t stream) {
    const float* action   = (const float*)d_in[0];
    const float* pos0     = (const float*)d_in[1];
    const float* vel0     = (const float*)d_in[2];
    const float* rest_len = (const float*)d_in[3];
    const int2*  edges    = (const int2*)d_in[4];
    float* out = (float*)d_out;

    // workspace layout
    char* ws = (char*)d_ws;
    size_t off = 0;
    fv4* rT     = (fv4*)(ws + off); off += (size_t)NE * 16;          // 6.4 MB
    int* deg    = (int*)(ws + off); off += (size_t)NV * 4;
    int* offs   = (int*)(ws + off); off += (size_t)(NV + 1) * 4;
    int* cursor = (int*)(ws + off); off += (size_t)NV * 4;
    int* bsum   = (int*)(ws + off); off += (size_t)(NBLK + 4) * 4;
    off = (off + 63) & ~(size_t)63;
    float4* pTa = (float4*)(ws + off); off += (size_t)NV * BB * 16;  // 6.4 MB
    float4* pTb = (float4*)(ws + off); off += (size_t)NV * BB * 16;  // 6.4 MB
    int* lo  = (int*)(ws + off);
    size_t lre_off = off + (size_t)2 * NE * 4;
    fv4* lre = (fv4*)(ws + lre_off);
    const bool fat = ws_size >= lre_off + (size_t)2 * NE * 16;       // needs ~36.5 MB total
    int2* lists = (int2*)(ws + off);                                 // lean overlay

    const int nNode3 = BB * NV * 3;
    const int nBV    = BB * NV;

    init_traj<<<(nNode3 + 255) / 256, 256, 0, stream>>>(pos0, vel0, out);
    posT_init<<<(nBV + 255) / 256, 256, 0, stream>>>(pos0, pTa);
    zero_deg<<<NBLK, 256, 0, stream>>>(deg);
    resteffT_kernel<<<(NE + 255) / 256, 256, 0, stream>>>(action, rest_len, rT);
    count_kernel<<<(NE + 255) / 256, 256, 0, stream>>>(edges, deg);
    scan_partials<<<NBLK, 256, 0, stream>>>(deg, bsum);
    scan_bsums<<<1, 512, 0, stream>>>(bsum);
    scan_write<<<NBLK, 256, 0, stream>>>(deg, bsum, offs, cursor);
    if (fat) {
        fill_fat<<<(NE + 255) / 256, 256, 0, stream>>>(edges, rT, cursor, lo, lre);
    } else {
        fill_lean<<<(NE + 255) / 256, 256, 0, stream>>>(edges, cursor, lists);
    }

    for (int s = 0; s < NSUB; ++s) {
        float4* pc = (s & 1) ? pTb : pTa;
        float4* pn = (s & 1) ? pTa : pTb;
        if (fat) {
            substep_il<<<(nBV + 255) / 256, 256, 0, stream>>>(
                out, pc, pn, lo, (const float*)lre, offs, s);
        } else {
            substep_lean<<<(nBV + 255) / 256, 256, 0, stream>>>(
                out, pc, pn, (const int*)lists, rT, offs, s);
        }
    }
}

// Round 7
// 392.393 us; speedup vs baseline: 12.2266x; 1.2081x over previous
//
#include <hip/hip_runtime.h>

// Problem constants (match reference)
#define NV 100000
#define NE 400000
#define BB 4
#define NSUB 10
constexpr float DT        = 0.01f;
constexpr float K_SPRING  = 1000.0f;
constexpr float DAMP      = 0.999f;
constexpr float ACT_SCALE = 0.1f;
constexpr float EPS       = 1e-6f;

#define VEL_BASE ((size_t)BB * (NSUB + 1) * NV * 3)
#define NBLK ((NV + 255) / 256)   // 391 blocks for per-node arrays

typedef float fv4 __attribute__((ext_vector_type(4)));

// ---------- one-time setup ----------

// One thread per (v,b): fills posT/velT (interleaved layout) and out slot 0.
__global__ void init_all(const float* __restrict__ pos0,
                         const float* __restrict__ vel0,
                         float* __restrict__ out,
                         float4* __restrict__ posT,
                         float4* __restrict__ velT) {
    int gid = blockIdx.x * blockDim.x + threadIdx.x;
    if (gid >= BB * NV) return;
    int b = gid & 3, v = gid >> 2;
    const float* ps = pos0 + ((size_t)b * NV + v) * 3;
    const float* vs = vel0 + ((size_t)b * NV + v) * 3;
    float px = ps[0], py = ps[1], pz = ps[2];
    float vx = vs[0], vy = vs[1], vz = vs[2];
    posT[gid] = make_float4(px, py, pz, 0.f);
    if (velT) velT[gid] = make_float4(vx, vy, vz, 0.f);
    size_t o = ((size_t)(b * (NSUB + 1)) * NV + v) * 3;   // slot 0
    out[o + 0] = px; out[o + 1] = py; out[o + 2] = pz;
    out[VEL_BASE + o + 0] = vx; out[VEL_BASE + o + 1] = vy; out[VEL_BASE + o + 2] = vz;
}

__global__ void zero_deg(int* __restrict__ deg) {
    int v = blockIdx.x * blockDim.x + threadIdx.x;
    if (v < NV) deg[v] = 0;
}

__global__ void count_kernel(const int2* __restrict__ edges, int* __restrict__ deg) {
    int e = blockIdx.x * blockDim.x + threadIdx.x;
    if (e >= NE) return;
    int2 ed = edges[e];
    atomicAdd(&deg[ed.x], 1);
    atomicAdd(&deg[ed.y], 1);
}

// --- 3-phase exclusive scan of deg[NV] -> offs[NV+1] (+cursor copy) ---

__global__ void scan_partials(const int* __restrict__ deg, int* __restrict__ bsum) {
    __shared__ int red[256];
    int i = blockIdx.x * 256 + threadIdx.x;
    red[threadIdx.x] = (i < NV) ? deg[i] : 0;
    __syncthreads();
    for (int off = 128; off > 0; off >>= 1) {
        if (threadIdx.x < off) red[threadIdx.x] += red[threadIdx.x + off];
        __syncthreads();
    }
    if (threadIdx.x == 0) bsum[blockIdx.x] = red[0];
}

__global__ void scan_bsums(int* __restrict__ bsum) {   // NBLK <= 512
    __shared__ int s[512];
    int t = threadIdx.x;
    s[t] = (t < NBLK) ? bsum[t] : 0;
    __syncthreads();
    for (int off = 1; off < 512; off <<= 1) {
        int v = (t >= off) ? s[t - off] : 0;
        __syncthreads();
        s[t] += v;
        __syncthreads();
    }
    if (t < NBLK) bsum[t] = (t == 0) ? 0 : s[t - 1];   // exclusive
}

__global__ void scan_write(const int* __restrict__ deg, const int* __restrict__ bsum,
                           int* __restrict__ offs, int* __restrict__ cursor) {
    __shared__ int s[256];
    int i = blockIdx.x * 256 + threadIdx.x;
    int d = (i < NV) ? deg[i] : 0;
    s[threadIdx.x] = d;
    __syncthreads();
    for (int off = 1; off < 256; off <<= 1) {          // inclusive scan
        int v = (threadIdx.x >= off) ? s[threadIdx.x - off] : 0;
        __syncthreads();
        s[threadIdx.x] += v;
        __syncthreads();
    }
    if (i <= NV - 1) {
        int excl = bsum[blockIdx.x] + s[threadIdx.x] - d;
        offs[i] = excl; cursor[i] = excl;
        if (i == NV - 1) offs[NV] = excl + d;
    }
}

// ---------- adjacency fill (computes rest_eff inline; no rT buffer) ----------
// lo[k] = other node, lre[k*4+b] = rest_eff for batch b
__global__ void fill_fat(const int2* __restrict__ edges,
                         const float* __restrict__ action,
                         const float* __restrict__ rest_len,
                         int* __restrict__ cursor,
                         int* __restrict__ lo,
                         fv4* __restrict__ lre) {
    int e = blockIdx.x * blockDim.x + threadIdx.x;
    if (e >= NE) return;
    int2 ed = edges[e];
    float rl = rest_len[e];
    fv4 re;
    #pragma unroll
    for (int b = 0; b < BB; ++b)
        re[b] = rl * (1.0f + ACT_SCALE * tanhf(action[b * NE + e]));
    int p = atomicAdd(&cursor[ed.x], 1);
    lo[p] = ed.y; lre[p] = re;
    int q = atomicAdd(&cursor[ed.y], 1);
    lo[q] = ed.x; lre[q] = re;
}

// ---------- per-substep fused gather + integrate ----------
// One thread per (node, batch); lanes 0-3 of a node cover b=0..3 so each
// neighbor gather is one fully-used 64B line: posT[o*4 + {0..3}].
// Chunk-of-4 unroll: 4 lo loads, then 4 lre + 4 posT gathers in flight.
template <bool VELT>
__global__ void substep_il(float* __restrict__ out,
                           const float4* __restrict__ posT,
                           float4* __restrict__ posTn,
                           const float4* __restrict__ velT,
                           float4* __restrict__ velTn,
                           const int* __restrict__ lo,
                           const float* __restrict__ lre,   // element view: [k*4 + b]
                           const int* __restrict__ offs, int s) {
    int gid = blockIdx.x * blockDim.x + threadIdx.x;
    if (gid >= BB * NV) return;
    int v = gid >> 2, b = gid & 3;

    float4 p = posT[gid];
    float fx = 0.f, fy = 0.f, fz = 0.f;

    int k = offs[v], end = offs[v + 1];

#define ACC(q, re) do { \
        float dx = (q).x - p.x, dy = (q).y - p.y, dz = (q).z - p.z; \
        float len = sqrtf(dx * dx + dy * dy + dz * dz + EPS); \
        float coef = K_SPRING * (len - (re)) / len; \
        fx += coef * dx; fy += coef * dy; fz += coef * dz; } while (0)

    for (; k + 3 < end; k += 4) {
        int o0 = __builtin_nontemporal_load(lo + k);
        int o1 = __builtin_nontemporal_load(lo + k + 1);
        int o2 = __builtin_nontemporal_load(lo + k + 2);
        int o3 = __builtin_nontemporal_load(lo + k + 3);
        float re0 = __builtin_nontemporal_load(lre + 4 * k + b);
        float re1 = __builtin_nontemporal_load(lre + 4 * k + 4 + b);
        float re2 = __builtin_nontemporal_load(lre + 4 * k + 8 + b);
        float re3 = __builtin_nontemporal_load(lre + 4 * k + 12 + b);
        float4 q0 = posT[o0 * 4 + b];
        float4 q1 = posT[o1 * 4 + b];
        float4 q2 = posT[o2 * 4 + b];
        float4 q3 = posT[o3 * 4 + b];
        ACC(q0, re0); ACC(q1, re1); ACC(q2, re2); ACC(q3, re3);
    }
    for (; k < end; ++k) {
        int   o  = __builtin_nontemporal_load(lo + k);
        float re = __builtin_nontemporal_load(lre + 4 * k + b);
        float4 q = posT[o * 4 + b];
        ACC(q, re);
    }
#undef ACC

    size_t cur = ((size_t)(b * (NSUB + 1) + s)) * NV * 3 + (size_t)v * 3;
    size_t nxt = cur + (size_t)NV * 3;

    float vcx, vcy, vcz;
    if (VELT) {
        float4 vc = velT[gid];
        vcx = vc.x; vcy = vc.y; vcz = vc.z;
    } else {
        vcx = out[VEL_BASE + cur + 0];
        vcy = out[VEL_BASE + cur + 1];
        vcz = out[VEL_BASE + cur + 2];
    }
    float vx = (vcx + DT * fx) * DAMP;
    float vy = (vcy + DT * (fy - 9.8f)) * DAMP;
    float vz = (vcz + DT * fz) * DAMP;
    float pxn = p.x + DT * vx, pyn = p.y + DT * vy, pzn = p.z + DT * vz;

    // pos trajectory is never re-read -> NT always; vel NT only when velT holds it
    __builtin_nontemporal_store(pxn, out + nxt + 0);
    __builtin_nontemporal_store(pyn, out + nxt + 1);
    __builtin_nontemporal_store(pzn, out + nxt + 2);
    if (VELT) {
        __builtin_nontemporal_store(vx, out + VEL_BASE + nxt + 0);
        __builtin_nontemporal_store(vy, out + VEL_BASE + nxt + 1);
        __builtin_nontemporal_store(vz, out + VEL_BASE + nxt + 2);
        velTn[gid] = make_float4(vx, vy, vz, 0.f);
    } else {
        out[VEL_BASE + nxt + 0] = vx;
        out[VEL_BASE + nxt + 1] = vy;
        out[VEL_BASE + nxt + 2] = vz;
    }
    posTn[gid] = make_float4(pxn, pyn, pzn, 0.f);
}

extern "C" void kernel_launch(void* const* d_in, const int* in_sizes, int n_in,
                              void* d_out, int out_size, void* d_ws, size_t ws_size,
                              hipStream_t stream) {
    const float* action   = (const float*)d_in[0];
    const float* pos0     = (const float*)d_in[1];
    const float* vel0     = (const float*)d_in[2];
    const float* rest_len = (const float*)d_in[3];
    const int2*  edges    = (const int2*)d_in[4];
    float* out = (float*)d_out;

    // workspace layout
    char* ws = (char*)d_ws;
    size_t off = 0;
    int* deg    = (int*)(ws + off); off += (size_t)NV * 4;
    int* offs   = (int*)(ws + off); off += (size_t)(NV + 1) * 4;
    int* cursor = (int*)(ws + off); off += (size_t)NV * 4;
    int* bsum   = (int*)(ws + off); off += (size_t)(NBLK + 4) * 4;
    off = (off + 63) & ~(size_t)63;
    float4* pTa = (float4*)(ws + off); off += (size_t)NV * BB * 16;  // 6.4 MB
    float4* pTb = (float4*)(ws + off); off += (size_t)NV * BB * 16;  // 6.4 MB
    int* lo  = (int*)(ws + off); off += (size_t)2 * NE * 4;          // 3.2 MB
    fv4* lre = (fv4*)(ws + off); off += (size_t)2 * NE * 16;         // 12.8 MB
    float4* vTa = (float4*)(ws + off);
    float4* vTb = vTa + (size_t)NV * BB;
    const bool velt = ws_size >= off + (size_t)2 * NV * BB * 16;     // +12.8 MB

    const int nBV = BB * NV;

    init_all<<<(nBV + 255) / 256, 256, 0, stream>>>(pos0, vel0, out, pTa, velt ? vTa : nullptr);
    zero_deg<<<NBLK, 256, 0, stream>>>(deg);
    count_kernel<<<(NE + 255) / 256, 256, 0, stream>>>(edges, deg);
    scan_partials<<<NBLK, 256, 0, stream>>>(deg, bsum);
    scan_bsums<<<1, 512, 0, stream>>>(bsum);
    scan_write<<<NBLK, 256, 0, stream>>>(deg, bsum, offs, cursor);
    fill_fat<<<(NE + 255) / 256, 256, 0, stream>>>(edges, action, rest_len, cursor, lo, lre);

    for (int s = 0; s < NSUB; ++s) {
        float4* pc = (s & 1) ? pTb : pTa;
        float4* pn = (s & 1) ? pTa : pTb;
        float4* vc = (s & 1) ? vTb : vTa;
        float4* vn = (s & 1) ? vTa : vTb;
        if (velt) {
            substep_il<true><<<(nBV + 255) / 256, 256, 0, stream>>>(
                out, pc, pn, vc, vn, lo, (const float*)lre, offs, s);
        } else {
            substep_il<false><<<(nBV + 255) / 256, 256, 0, stream>>>(
                out, pc, pn, nullptr, nullptr, lo, (const float*)lre, offs, s);
        }
    }
}

// Round 8
// 392.206 us; speedup vs baseline: 12.2324x; 1.0005x over previous
//
#include <hip/hip_runtime.h>

// Problem constants (match reference)
#define NV 100000
#define NE 400000
#define BB 4
#define NSUB 10
constexpr float DT        = 0.01f;
constexpr float K_SPRING  = 1000.0f;
constexpr float DAMP      = 0.999f;
constexpr float ACT_SCALE = 0.1f;
constexpr float EPS       = 1e-6f;

#define VEL_BASE ((size_t)BB * (NSUB + 1) * NV * 3)
#define NBLK ((NV + 255) / 256)        // 391 blocks for per-node arrays
#define PADCAP (2 * NE + 3 * NV + 64)  // padded slot capacity

typedef float fv4 __attribute__((ext_vector_type(4)));

// ---------- one-time setup ----------

// One thread per (v,b): fills posT/velT (interleaved layout) and out slot 0.
__global__ void init_all(const float* __restrict__ pos0,
                         const float* __restrict__ vel0,
                         float* __restrict__ out,
                         float4* __restrict__ posT,
                         float4* __restrict__ velT) {
    int gid = blockIdx.x * blockDim.x + threadIdx.x;
    if (gid >= BB * NV) return;
    int b = gid & 3, v = gid >> 2;
    const float* ps = pos0 + ((size_t)b * NV + v) * 3;
    const float* vs = vel0 + ((size_t)b * NV + v) * 3;
    float px = ps[0], py = ps[1], pz = ps[2];
    float vx = vs[0], vy = vs[1], vz = vs[2];
    posT[gid] = make_float4(px, py, pz, 0.f);
    if (velT) velT[gid] = make_float4(vx, vy, vz, 0.f);
    size_t o = ((size_t)(b * (NSUB + 1)) * NV + v) * 3;   // slot 0
    out[o + 0] = px; out[o + 1] = py; out[o + 2] = pz;
    out[VEL_BASE + o + 0] = vx; out[VEL_BASE + o + 1] = vy; out[VEL_BASE + o + 2] = vz;
}

__global__ void zero_deg(int* __restrict__ deg) {
    int v = blockIdx.x * blockDim.x + threadIdx.x;
    if (v < NV) deg[v] = 0;
}

__global__ void count_kernel(const int2* __restrict__ edges, int* __restrict__ deg) {
    int e = blockIdx.x * blockDim.x + threadIdx.x;
    if (e >= NE) return;
    int2 ed = edges[e];
    atomicAdd(&deg[ed.x], 1);
    atomicAdd(&deg[ed.y], 1);
}

// --- 3-phase exclusive scan over PADDED degrees -> offs[NV+1] (+cursor) ---
__device__ __forceinline__ int padded(int d) { return (d + 3) & ~3; }

__global__ void scan_partials(const int* __restrict__ deg, int* __restrict__ bsum) {
    __shared__ int red[256];
    int i = blockIdx.x * 256 + threadIdx.x;
    red[threadIdx.x] = (i < NV) ? padded(deg[i]) : 0;
    __syncthreads();
    for (int off = 128; off > 0; off >>= 1) {
        if (threadIdx.x < off) red[threadIdx.x] += red[threadIdx.x + off];
        __syncthreads();
    }
    if (threadIdx.x == 0) bsum[blockIdx.x] = red[0];
}

__global__ void scan_bsums(int* __restrict__ bsum) {   // NBLK <= 512
    __shared__ int s[512];
    int t = threadIdx.x;
    s[t] = (t < NBLK) ? bsum[t] : 0;
    __syncthreads();
    for (int off = 1; off < 512; off <<= 1) {
        int v = (t >= off) ? s[t - off] : 0;
        __syncthreads();
        s[t] += v;
        __syncthreads();
    }
    if (t < NBLK) bsum[t] = (t == 0) ? 0 : s[t - 1];   // exclusive
}

__global__ void scan_write(const int* __restrict__ deg, const int* __restrict__ bsum,
                           int* __restrict__ offs, int* __restrict__ cursor) {
    __shared__ int s[256];
    int i = blockIdx.x * 256 + threadIdx.x;
    int d = (i < NV) ? padded(deg[i]) : 0;
    s[threadIdx.x] = d;
    __syncthreads();
    for (int off = 1; off < 256; off <<= 1) {          // inclusive scan
        int v = (threadIdx.x >= off) ? s[threadIdx.x - off] : 0;
        __syncthreads();
        s[threadIdx.x] += v;
        __syncthreads();
    }
    if (i <= NV - 1) {
        int excl = bsum[blockIdx.x] + s[threadIdx.x] - d;
        offs[i] = excl; cursor[i] = excl;
        if (i == NV - 1) offs[NV] = excl + d;
    }
}

// ---------- adjacency fill ----------
// lo[k] = other node, lre[k*4+b] = K_SPRING * rest_eff (pre-scaled)
__global__ void fill_fat(const int2* __restrict__ edges,
                         const float* __restrict__ action,
                         const float* __restrict__ rest_len,
                         int* __restrict__ cursor,
                         int* __restrict__ lo,
                         fv4* __restrict__ lre) {
    int e = blockIdx.x * blockDim.x + threadIdx.x;
    if (e >= NE) return;
    int2 ed = edges[e];
    float krl = K_SPRING * rest_len[e];
    fv4 re;
    #pragma unroll
    for (int b = 0; b < BB; ++b)
        re[b] = krl * (1.0f + ACT_SCALE * tanhf(action[b * NE + e]));
    int p = atomicAdd(&cursor[ed.x], 1);
    lo[p] = ed.y; lre[p] = re;
    int q = atomicAdd(&cursor[ed.y], 1);
    lo[q] = ed.x; lre[q] = re;
}

// pad each node's list to the next multiple of 4 with zero-contribution
// self-edges (d=0 -> coef*0 = 0 regardless of coef).
__global__ void pad_fill(const int* __restrict__ cursor,
                         const int* __restrict__ offs,
                         int* __restrict__ lo,
                         fv4* __restrict__ lre) {
    int v = blockIdx.x * blockDim.x + threadIdx.x;
    if (v >= NV) return;
    int k = cursor[v], end = offs[v + 1];
    for (; k < end; ++k) {
        lo[k] = v;
        lre[k] = (fv4)(0.f);
    }
}

// ---------- per-substep fused gather + integrate ----------
// One thread per (node, batch); lanes 0-3 of a node cover b=0..3 so each
// neighbor gather is one fully-used 64B line: posT[o*4 + {0..3}].
// List length is a multiple of 4 -> single chunk-4 loop, no remainder.
// coef = K*(len-re)/len == K - (K*re)*rsqrt(d2+EPS); lre holds K*re.
template <bool VELT>
__global__ void substep_il(float* __restrict__ out,
                           const float4* __restrict__ posT,
                           float4* __restrict__ posTn,
                           float4* __restrict__ velT,   // single buffer: velT[gid] owned by this thread
                           const int* __restrict__ lo,
                           const float* __restrict__ lre,   // element view: [k*4 + b]
                           const int* __restrict__ offs, int s) {
    int gid = blockIdx.x * blockDim.x + threadIdx.x;
    if (gid >= BB * NV) return;
    int v = gid >> 2, b = gid & 3;

    float4 p = posT[gid];
    float fx = 0.f, fy = 0.f, fz = 0.f;

    int k = offs[v], end = offs[v + 1];

#define ACC(q, kre) do { \
        float dx = (q).x - p.x, dy = (q).y - p.y, dz = (q).z - p.z; \
        float d2 = fmaf(dx, dx, fmaf(dy, dy, fmaf(dz, dz, EPS))); \
        float rs = rsqrtf(d2); \
        float t  = fmaf(-(kre), rs, K_SPRING); \
        fx = fmaf(t, dx, fx); fy = fmaf(t, dy, fy); fz = fmaf(t, dz, fz); } while (0)

    for (; k < end; k += 4) {
        int o0 = __builtin_nontemporal_load(lo + k);
        int o1 = __builtin_nontemporal_load(lo + k + 1);
        int o2 = __builtin_nontemporal_load(lo + k + 2);
        int o3 = __builtin_nontemporal_load(lo + k + 3);
        float r0 = __builtin_nontemporal_load(lre + 4 * k + b);
        float r1 = __builtin_nontemporal_load(lre + 4 * k + 4 + b);
        float r2 = __builtin_nontemporal_load(lre + 4 * k + 8 + b);
        float r3 = __builtin_nontemporal_load(lre + 4 * k + 12 + b);
        float4 q0 = posT[o0 * 4 + b];
        float4 q1 = posT[o1 * 4 + b];
        float4 q2 = posT[o2 * 4 + b];
        float4 q3 = posT[o3 * 4 + b];
        ACC(q0, r0); ACC(q1, r1); ACC(q2, r2); ACC(q3, r3);
    }
#undef ACC

    size_t cur = ((size_t)(b * (NSUB + 1) + s)) * NV * 3 + (size_t)v * 3;
    size_t nxt = cur + (size_t)NV * 3;

    float vcx, vcy, vcz;
    if (VELT) {
        float4 vc = velT[gid];
        vcx = vc.x; vcy = vc.y; vcz = vc.z;
    } else {
        vcx = out[VEL_BASE + cur + 0];
        vcy = out[VEL_BASE + cur + 1];
        vcz = out[VEL_BASE + cur + 2];
    }
    float vx = (vcx + DT * fx) * DAMP;
    float vy = (vcy + DT * (fy - 9.8f)) * DAMP;
    float vz = (vcz + DT * fz) * DAMP;
    float pxn = p.x + DT * vx, pyn = p.y + DT * vy, pzn = p.z + DT * vz;

    // pos trajectory never re-read -> NT; vel traj NT only when velT holds state
    __builtin_nontemporal_store(pxn, out + nxt + 0);
    __builtin_nontemporal_store(pyn, out + nxt + 1);
    __builtin_nontemporal_store(pzn, out + nxt + 2);
    if (VELT) {
        __builtin_nontemporal_store(vx, out + VEL_BASE + nxt + 0);
        __builtin_nontemporal_store(vy, out + VEL_BASE + nxt + 1);
        __builtin_nontemporal_store(vz, out + VEL_BASE + nxt + 2);
        velT[gid] = make_float4(vx, vy, vz, 0.f);
    } else {
        out[VEL_BASE + nxt + 0] = vx;
        out[VEL_BASE + nxt + 1] = vy;
        out[VEL_BASE + nxt + 2] = vz;
    }
    posTn[gid] = make_float4(pxn, pyn, pzn, 0.f);
}

extern "C" void kernel_launch(void* const* d_in, const int* in_sizes, int n_in,
                              void* d_out, int out_size, void* d_ws, size_t ws_size,
                              hipStream_t stream) {
    const float* action   = (const float*)d_in[0];
    const float* pos0     = (const float*)d_in[1];
    const float* vel0     = (const float*)d_in[2];
    const float* rest_len = (const float*)d_in[3];
    const int2*  edges    = (const int2*)d_in[4];
    float* out = (float*)d_out;

    // workspace layout
    char* ws = (char*)d_ws;
    size_t off = 0;
    int* deg    = (int*)(ws + off); off += (size_t)NV * 4;
    int* offs   = (int*)(ws + off); off += (size_t)(NV + 1) * 4;
    int* cursor = (int*)(ws + off); off += (size_t)NV * 4;
    int* bsum   = (int*)(ws + off); off += (size_t)(NBLK + 4) * 4;
    off = (off + 63) & ~(size_t)63;
    float4* pTa = (float4*)(ws + off); off += (size_t)NV * BB * 16;  // 6.4 MB
    float4* pTb = (float4*)(ws + off); off += (size_t)NV * BB * 16;  // 6.4 MB
    int* lo  = (int*)(ws + off); off += (size_t)PADCAP * 4;          // 4.4 MB
    fv4* lre = (fv4*)(ws + off); off += (size_t)PADCAP * 16;         // 17.6 MB
    float4* vT = (float4*)(ws + off);
    const bool velt = ws_size >= off + (size_t)NV * BB * 16;         // +6.4 MB -> ~42.5 MB total

    const int nBV = BB * NV;

    init_all<<<(nBV + 255) / 256, 256, 0, stream>>>(pos0, vel0, out, pTa, velt ? vT : nullptr);
    zero_deg<<<NBLK, 256, 0, stream>>>(deg);
    count_kernel<<<(NE + 255) / 256, 256, 0, stream>>>(edges, deg);
    scan_partials<<<NBLK, 256, 0, stream>>>(deg, bsum);
    scan_bsums<<<1, 512, 0, stream>>>(bsum);
    scan_write<<<NBLK, 256, 0, stream>>>(deg, bsum, offs, cursor);
    fill_fat<<<(NE + 255) / 256, 256, 0, stream>>>(edges, action, rest_len, cursor, lo, lre);
    pad_fill<<<NBLK, 256, 0, stream>>>(cursor, offs, lo, lre);

    for (int s = 0; s < NSUB; ++s) {
        float4* pc = (s & 1) ? pTb : pTa;
        float4* pn = (s & 1) ? pTa : pTb;
        if (velt) {
            substep_il<true><<<(nBV + 255) / 256, 256, 0, stream>>>(
                out, pc, pn, vT, lo, (const float*)lre, offs, s);
        } else {
            substep_il<false><<<(nBV + 255) / 256, 256, 0, stream>>>(
                out, pc, pn, nullptr, lo, (const float*)lre, offs, s);
        }
    }
}